// Round 17
// baseline (159.713 us; speedup 1.0000x reference)
//
#include <hip/hip_runtime.h>
#include <stdint.h>

#define L_SEQ 2048
#define BATCH 2
#define DMODEL 512
#define PROJ 1024
#define NST 32
#define NCATU 1088  // 1024 (Wd) + 32 (WB) + 32 (WC)
#define ROWS (BATCH*L_SEQ)  // 4096
#define THRESH 50.0f        // suffix cutoff (nats)

typedef float f32x4 __attribute__((ext_vector_type(4)));
typedef short short8 __attribute__((ext_vector_type(8)));

__device__ inline float bf2f(unsigned short u){ uint32_t x=((uint32_t)u)<<16; float f; __builtin_memcpy(&f,&x,4); return f; }
__device__ inline unsigned short f2bf(float f){ uint32_t x; __builtin_memcpy(&x,&f,4); uint32_t r=x+0x7FFFu+((x>>16)&1u); return (unsigned short)(r>>16); }
__device__ inline float siluf(float x){ return x/(1.f+__expf(-x)); }
__device__ inline float softplusf(float x){ return x>20.f? x : log1pf(__expf(x)); }

#define AS1(p) ((const __attribute__((address_space(1))) void*)(p))
#define AS3(p) ((__attribute__((address_space(3))) void*)(p))

template<int N> __device__ inline void wait_vmcnt(){
  if constexpr (N==0)      asm volatile("s_waitcnt vmcnt(0)" ::: "memory");
  else if constexpr (N==4) asm volatile("s_waitcnt vmcnt(4)" ::: "memory");
  else if constexpr (N==8) asm volatile("s_waitcnt vmcnt(8)" ::: "memory");
  else                     asm volatile("s_waitcnt vmcnt(12)" ::: "memory");
}

// ---------------- merged weight-prep (LDS-tiled transposes) + LayerNorm ----------------
__global__ __launch_bounds__(256)
void prep_ln_kernel(const float* __restrict__ W1, const float* __restrict__ b1,
                    const float* __restrict__ W2, const float* __restrict__ b2,
                    const float* __restrict__ Wd, const float* __restrict__ bd,
                    const float* __restrict__ WB, const float* __restrict__ bB,
                    const float* __restrict__ WC, const float* __restrict__ bC,
                    const float* __restrict__ W3,
                    unsigned short* __restrict__ W12t, unsigned short* __restrict__ Wcatt,
                    unsigned short* __restrict__ W3t, float* __restrict__ bias12,
                    float* __restrict__ biascat,
                    const float* __restrict__ x, const float* __restrict__ ln_g,
                    const float* __restrict__ ln_b, unsigned short* __restrict__ H)
{
  __shared__ float tile[32][33];
  int bid = blockIdx.x;
  int lx = threadIdx.x & 31, ly = threadIdx.x >> 5;   // ly 0..7
  if (bid < 1024) {                    // W12t[2048][512] = (W1||W2)[512][2048]^T
    int kt = bid & 15, nt = bid >> 4;
    int k0 = kt*32, n0 = nt*32;
    const float* S = (n0 < 1024) ? W1 : W2;
    int nc = (n0 < 1024) ? n0 : n0 - 1024;
#pragma unroll
    for (int i=0;i<4;i++)
      tile[ly+i*8][lx] = S[(size_t)(k0+ly+i*8)*1024 + nc + lx];
    __syncthreads();
#pragma unroll
    for (int i=0;i<4;i++)
      W12t[(size_t)(n0+ly+i*8)*512 + k0 + lx] = f2bf(tile[lx][ly+i*8]);
    return;
  }
  if (bid < 2112) {                    // Wcatt[1088][1024] = (Wd|WB|WC)[1024][1088]^T
    int t = bid - 1024;
    int kt = t & 31, nt = t >> 5;      // 32 k-tiles, 34 n-tiles
    int k0 = kt*32, n0 = nt*32;
#pragma unroll
    for (int i=0;i<4;i++){
      int k = k0 + ly + i*8;
      float v;
      if (n0 < 1024)       v = Wd[(size_t)k*1024 + n0 + lx];
      else if (n0 == 1024) v = WB[(size_t)k*32 + lx];
      else                 v = WC[(size_t)k*32 + lx];
      tile[ly+i*8][lx] = v;
    }
    __syncthreads();
#pragma unroll
    for (int i=0;i<4;i++)
      Wcatt[(size_t)(n0+ly+i*8)*1024 + k0 + lx] = f2bf(tile[lx][ly+i*8]);
    return;
  }
  if (bid < 2624) {                    // W3t[512][1024] = W3[1024][512]^T
    int t = bid - 2112;
    int kt = t & 31, nt = t >> 5;      // 32 k-tiles, 16 n-tiles
    int k0 = kt*32, n0 = nt*32;
#pragma unroll
    for (int i=0;i<4;i++)
      tile[ly+i*8][lx] = W3[(size_t)(k0+ly+i*8)*512 + n0 + lx];
    __syncthreads();
#pragma unroll
    for (int i=0;i<4;i++)
      W3t[(size_t)(n0+ly+i*8)*1024 + k0 + lx] = f2bf(tile[lx][ly+i*8]);
    return;
  }
  if (bid < 2637) {
    int j = (bid - 2624)*256 + threadIdx.x;
    if (j < 2048) { bias12[j] = (j < 1024) ? b1[j] : b2[j-1024]; return; }
    j -= 2048;
    if (j < NCATU) biascat[j] = (j < 1024) ? bd[j] : (j < 1056) ? bB[j-1024] : bC[j-1056];
    return;
  }
  // LayerNorm
  int row = (bid - 2637)*4 + (threadIdx.x >> 6);
  int lane = threadIdx.x & 63;
  const float4* xr = (const float4*)(x + (size_t)row*DMODEL);
  float4 v0 = xr[lane];
  float4 v1 = xr[lane+64];
  float s = v0.x+v0.y+v0.z+v0.w + v1.x+v1.y+v1.z+v1.w;
  float q = v0.x*v0.x+v0.y*v0.y+v0.z*v0.z+v0.w*v0.w
          + v1.x*v1.x+v1.y*v1.y+v1.z*v1.z+v1.w*v1.w;
#pragma unroll
  for (int m=32;m>0;m>>=1){ s += __shfl_xor(s,m); q += __shfl_xor(q,m); }
  float mu = s*(1.f/DMODEL);
  float var = q*(1.f/DMODEL) - mu*mu;
  float rs = rsqrtf(var + 1e-3f);
  int c0 = lane*4, c1 = 256 + lane*4;
  float4 g0 = *(const float4*)&ln_g[c0]; float4 g1 = *(const float4*)&ln_g[c1];
  float4 t0 = *(const float4*)&ln_b[c0]; float4 t1 = *(const float4*)&ln_b[c1];
  ushort4 o0, o1;
  o0.x = f2bf((v0.x-mu)*rs*g0.x + t0.x);
  o0.y = f2bf((v0.y-mu)*rs*g0.y + t0.y);
  o0.z = f2bf((v0.z-mu)*rs*g0.z + t0.z);
  o0.w = f2bf((v0.w-mu)*rs*g0.w + t0.w);
  o1.x = f2bf((v1.x-mu)*rs*g1.x + t1.x);
  o1.y = f2bf((v1.y-mu)*rs*g1.y + t1.y);
  o1.z = f2bf((v1.z-mu)*rs*g1.z + t1.z);
  o1.w = f2bf((v1.w-mu)*rs*g1.w + t1.w);
  *(ushort4*)&H[(size_t)row*DMODEL + c0] = o0;
  *(ushort4*)&H[(size_t)row*DMODEL + c1] = o1;
}

// ---------------- 64x64 bf16 GEMM: triple-buffer, counted vmcnt (measured-best config) ----------------
// MODE 1: +bias[col]; col<1024 -> P12n bf16, col>=1024 -> x2bf = silu (Cv2).
// MODE 2 (transposed): +bias[row], softplus row<1024 -> fp32 CT[row*N+col].
// MODE 5: raw fp32 partial at Cv + z*M*N (split-K).
template<int MODE>
__global__ __launch_bounds__(256)
void gemm64(const unsigned short* __restrict__ A, const unsigned short* __restrict__ Bt,
            void* __restrict__ Cv, void* __restrict__ Cv2, const float* __restrict__ bias,
            int M, int N, int K, int Kfull)
{
  constexpr int BK = 64;
  constexpr int LPT = 4;
  __shared__ unsigned short As[3][64*BK];
  __shared__ unsigned short Bs[3][64*BK];
  int tid = threadIdx.x;
  int lane = tid & 63, wid = tid >> 6;
  int wm = wid >> 1, wn = wid & 1;
  int gx = gridDim.x;
  int nwg = gx * gridDim.y;
  int L = blockIdx.y*gx + blockIdx.x;
  int W = (L & 7)*(nwg >> 3) + (L >> 3);
  int bx = W % gx, by = W / gx;
  int m0 = bx*64, n0 = by*64;
  int kofs = blockIdx.z*K;

  f32x4 acc[2][2];
#pragma unroll
  for (int i=0;i<2;i++)
#pragma unroll
    for (int j=0;j<2;j++)
#pragma unroll
      for (int e=0;e<4;e++) acc[i][j][e] = 0.f;

  const unsigned short* ap[2];
  const unsigned short* bp[2];
#pragma unroll
  for (int j=0;j<2;j++){
    int s = tid + j*256;
    int row = s >> 3, kc = ((s & 7) ^ (row & 7)) * 8;
    ap[j] = A + (size_t)(m0+row)*Kfull + kofs + kc;
    bp[j] = Bt + (size_t)(n0+row)*Kfull + kofs + kc;
  }
  auto stage = [&](int buf){
#pragma unroll
    for (int j=0;j<2;j++){
      __builtin_amdgcn_global_load_lds(AS1(ap[j]), AS3(&As[buf][(size_t)(j*256 + wid*64)*8]), 16, 0, 0);
      ap[j] += BK;
    }
#pragma unroll
    for (int j=0;j<2;j++){
      __builtin_amdgcn_global_load_lds(AS1(bp[j]), AS3(&Bs[buf][(size_t)(j*256 + wid*64)*8]), 16, 0, 0);
      bp[j] += BK;
    }
  };
  stage(0); stage(1);
  int T = K/BK;
  int rb = 0, wb = 2;
  int r = lane & 15, kb = lane >> 4;
  for (int t = 0; t < T; ++t) {
    if (t+1 < T) wait_vmcnt<LPT>();
    else         wait_vmcnt<0>();
    __builtin_amdgcn_s_barrier();
    if (t+2 < T) { stage(wb); wb = (wb==2)?0:wb+1; }
#pragma unroll
    for (int ks=0; ks<2; ++ks) {
      int cx = (ks*4 + kb) ^ (r & 7);
      short8 af[2], bfr[2];
#pragma unroll
      for (int i=0;i<2;i++) af[i]  = *(const short8*)&As[rb][((wm*32 + i*16 + r)*8 + cx)*8];
#pragma unroll
      for (int j=0;j<2;j++) bfr[j] = *(const short8*)&Bs[rb][((wn*32 + j*16 + r)*8 + cx)*8];
      __builtin_amdgcn_s_setprio(1);
#pragma unroll
      for (int i=0;i<2;i++)
#pragma unroll
        for (int j=0;j<2;j++)
          acc[i][j] = __builtin_amdgcn_mfma_f32_16x16x32_bf16(af[i], bfr[j], acc[i][j], 0,0,0);
      __builtin_amdgcn_s_setprio(0);
    }
    rb = (rb==2)?0:rb+1;
  }
  int rr = (lane >> 4)*4, cc = lane & 15;
#pragma unroll
  for (int i=0;i<2;i++)
#pragma unroll
    for (int j=0;j<2;j++) {
      int col = n0 + wn*32 + j*16 + cc;
#pragma unroll
      for (int e=0;e<4;e++) {
        int row = m0 + wm*32 + i*16 + rr + e;
        float v = acc[i][j][e];
        if constexpr (MODE == 1) {
          v += bias[col];
          if (col < 1024) ((unsigned short*)Cv)[(size_t)row*1024 + col] = f2bf(v);
          else            ((unsigned short*)Cv2)[(size_t)row*1024 + col - 1024] = f2bf(siluf(v));
        } else if constexpr (MODE == 2) {
          v += bias[row];
          if (row < 1024) v = softplusf(v);
          ((float*)Cv)[(size_t)row*N + col] = v;
        } else {
          ((float*)Cv)[(size_t)blockIdx.z*M*N + (size_t)row*N + col] = v;
        }
      }
    }
}

// ---------------- split-K reduce + bias + residual ----------------
__global__ __launch_bounds__(256)
void reduce_kernel(const float* __restrict__ P, const float* __restrict__ x,
                   const float* __restrict__ b3, float* __restrict__ out)
{
  size_t i = ((size_t)blockIdx.x*256 + threadIdx.x)*4;
  int col = (int)(i & 511);
  float4 a = *(const float4*)&P[i];
  float4 b = *(const float4*)&P[(size_t)ROWS*512 + i];
  float4 xv = *(const float4*)&x[i];
  float4 bv = *(const float4*)&b3[col];
  float4 o;
  o.x = a.x + b.x + xv.x + bv.x;
  o.y = a.y + b.y + xv.y + bv.y;
  o.z = a.z + b.z + xv.z + bv.z;
  o.w = a.w + b.w + xv.w + bv.w;
  *(float4*)&out[i] = o;
}

// ---------------- causal depthwise conv (K=4) + SiLU (u path only) ----------------
__global__ __launch_bounds__(256)
void conv_silu_kernel(const unsigned short* __restrict__ P12n, const float* __restrict__ ck,
                      const float* __restrict__ cb, unsigned short* __restrict__ ubf)
{
  int gid = blockIdx.x*256 + threadIdx.x;   // ROWS * 256 tasks
  int c = (gid & 255)*4;
  int row = gid >> 8;
  int l = row & (L_SEQ-1);
  float4 bv = *(const float4*)&cb[c];
  float r0=bv.x, r1=bv.y, r2=bv.z, r3=bv.w;
#pragma unroll
  for (int t=0;t<4;t++){
    int lsrc = l - 3 + t;
    if (lsrc >= 0) {
      ushort4 xv = *(const ushort4*)&P12n[(size_t)(row-3+t)*1024 + c];
      float4 kv = *(const float4*)&ck[t*PROJ + c];
      r0 = fmaf(bf2f(xv.x),kv.x,r0);
      r1 = fmaf(bf2f(xv.y),kv.y,r1);
      r2 = fmaf(bf2f(xv.z),kv.z,r2);
      r3 = fmaf(bf2f(xv.w),kv.w,r3);
    }
  }
  ushort4 o;
  o.x=f2bf(siluf(r0)); o.y=f2bf(siluf(r1)); o.z=f2bf(siluf(r2)); o.w=f2bf(siluf(r3));
  *(ushort4*)&ubf[(size_t)row*PROJ + c] = o;
}

// ---------------- bf16 transpose: src[4096][1024] -> dst[1024][4096] (u and x2) ----------------
__global__ __launch_bounds__(256)
void utrans_kernel(const unsigned short* __restrict__ u, const unsigned short* __restrict__ x2,
                   unsigned short* __restrict__ uT, unsigned short* __restrict__ x2T)
{
  __shared__ unsigned short tile[32][33];
  const unsigned short* src = blockIdx.z ? x2 : u;
  unsigned short* dst = blockIdx.z ? x2T : uT;
  int r0 = blockIdx.x*32, c0 = blockIdx.y*32;
  int lx = threadIdx.x & 31, ly = threadIdx.x >> 5;
#pragma unroll
  for (int i=0;i<4;i++)
    tile[ly+i*8][lx] = src[(size_t)(r0+ly+i*8)*1024 + c0 + lx];
  __syncthreads();
#pragma unroll
  for (int i=0;i<4;i++)
    dst[(size_t)(c0+ly+i*8)*ROWS + r0 + lx] = tile[lx][ly+i*8];
}

// ---------------- zmul_pre: z = u*Dskip*x2 everywhere, COALESCED (sscan overwrites tail) ----------------
__global__ __launch_bounds__(256)
void zmul_pre_kernel(const unsigned short* __restrict__ ubf, const unsigned short* __restrict__ x2bf,
                     const float* __restrict__ Dskip, unsigned short* __restrict__ zbf)
{
  size_t i = ((size_t)blockIdx.x*256 + threadIdx.x)*4;
  int d = (int)(i & (PROJ-1));
  ushort4 uu = *(const ushort4*)&ubf[i];
  ushort4 xx = *(const ushort4*)&x2bf[i];
  float4 Dv = *(const float4*)&Dskip[d];
  ushort4 o;
  o.x = f2bf(bf2f(uu.x)*Dv.x*bf2f(xx.x));
  o.y = f2bf(bf2f(uu.y)*Dv.y*bf2f(xx.y));
  o.z = f2bf(bf2f(uu.z)*Dv.z*bf2f(xx.z));
  o.w = f2bf(bf2f(uu.w)*Dv.w*bf2f(xx.w));
  *(ushort4*)&zbf[i] = o;
}

// ---------------- chunked suffix-sum + gated scan, one block per (b,d) ----------------
// All scan-side streams (delta/B/C via CT, u via uT, x2 via x2T) are CONTIGUOUS in l,
// and each pass register-double-buffers the next l-block's loads so latency hides
// under the serial s-chain (r16 lesson: strided in-chain loads = 45us floor).
__global__ __launch_bounds__(256)
void sscan_kernel(const float* __restrict__ CT, const unsigned short* __restrict__ uT,
                  const unsigned short* __restrict__ x2T, const float* __restrict__ Dskip,
                  const float* __restrict__ A_log, unsigned short* __restrict__ zbf)
{
  __shared__ float ps[256];
  __shared__ float suf8sh[256];
  __shared__ int   cs[256];
  __shared__ float Alds[8][32];
  __shared__ float Slds[8][32];
  __shared__ int baseSh;
  int tid = threadIdx.x;
  int G = blockIdx.x;
  int b = G >> 10, d = G & 1023;
  const float* dT = CT + (size_t)d*ROWS + b*L_SEQ;   // softplus'd delta row

  // ---- phase A: suffix sums at 8-boundaries + global base ----
  float4 a0 = *(const float4*)&dT[tid*8];
  float4 a1 = *(const float4*)&dT[tid*8+4];
  float vals[8] = {a0.x,a0.y,a0.z,a0.w,a1.x,a1.y,a1.z,a1.w};
  float part = 0.f;
#pragma unroll
  for (int i=0;i<8;i++) part += vals[i];
  ps[tid] = part; __syncthreads();
  for (int off=1; off<256; off<<=1){
    float v = (tid >= off) ? ps[tid-off] : 0.f;
    __syncthreads();
    ps[tid] += v;
    __syncthreads();
  }
  float Tot = ps[255];
  float prefx = ps[tid] - part;
  suf8sh[tid] = Tot - prefx;                 // suffix incl. position 8*tid
  int cnt = 0; float run = prefx;
#pragma unroll
  for (int i=0;i<8;i++){ cnt += (Tot - run >= THRESH) ? 1 : 0; run += vals[i]; }
  cs[tid] = cnt; __syncthreads();
  for (int off=128; off>0; off>>=1){ if (tid < off) cs[tid] += cs[tid+off]; __syncthreads(); }
  if (tid == 0) {
    int total = cs[0];
    int l0 = total > 0 ? total-1 : 0;
    baseSh = l0 & ~7;
  }
  __syncthreads();
  int base = baseSh;

  int n = tid & 31, seg = tid >> 5;
  int segStart = seg*256, segEnd = segStart + 256;
  float np1 = __expf(A_log[d*NST + n]);      // -A[d,n] = n+1
  float Ds = Dskip[d];
  const float* Br = CT + (size_t)(1024+n)*ROWS + b*L_SEQ;
  const float* Cr = CT + (size_t)(1056+n)*ROWS + b*L_SEQ;
  const unsigned short* ub = uT  + (size_t)d*ROWS + b*L_SEQ;   // contiguous in l
  const unsigned short* xb = x2T + (size_t)d*ROWS + b*L_SEQ;
  unsigned short* zb = zbf + (size_t)b*L_SEQ*PROJ + d;

  bool active = segEnd > base;
  int sFirst = base >> 8;
  int lstart = max(segStart, base);

  // ---- pass 1: local (Aprod, S) for active segs that feed a later segment ----
  if (active && seg < 7) {
    float s = 0.f, Ap = 1.f;
    int l = lstart;
    float4 d0=*(const float4*)&dT[l], d1=*(const float4*)&dT[l+4];
    float4 B0=*(const float4*)&Br[l], B1=*(const float4*)&Br[l+4];
    ushort4 u0=*(const ushort4*)&ub[l], u1=*(const ushort4*)&ub[l+4];
    while (l < segEnd) {
      int ln = l + 8;
      float4 nd0,nd1,nB0,nB1; ushort4 nu0,nu1;
      if (ln < segEnd) {
        nd0=*(const float4*)&dT[ln]; nd1=*(const float4*)&dT[ln+4];
        nB0=*(const float4*)&Br[ln]; nB1=*(const float4*)&Br[ln+4];
        nu0=*(const ushort4*)&ub[ln]; nu1=*(const ushort4*)&ub[ln+4];
      }
      float dl[8] = {d0.x,d0.y,d0.z,d0.w,d1.x,d1.y,d1.z,d1.w};
      float Bv[8] = {B0.x,B0.y,B0.z,B0.w,B1.x,B1.y,B1.z,B1.w};
      float uu[8] = {bf2f(u0.x),bf2f(u0.y),bf2f(u0.z),bf2f(u0.w),
                     bf2f(u1.x),bf2f(u1.y),bf2f(u1.z),bf2f(u1.w)};
#pragma unroll
      for (int t=0;t<8;t++){
        float decay = __expf(-dl[t]*np1);
        s = fmaf(decay, s, dl[t]*uu[t]*Bv[t]);
        Ap *= decay;
      }
      l = ln;
      d0=nd0; d1=nd1; B0=nB0; B1=nB1; u0=nu0; u1=nu1;
    }
    Alds[seg][n] = Ap; Slds[seg][n] = s;
  }
  __syncthreads();

  // ---- combine: incoming state for this segment ----
  float sin = 0.f;
  if (active) {
    for (int c = sFirst; c < seg; ++c)
      sin = fmaf(Alds[c][n], sin, Slds[c][n]);
  }

  // ---- pass 3: outputs (rows >= base only), double-buffered loads ----
  if (active) {
    float s = sin;
    int l = lstart;
    float4 d0=*(const float4*)&dT[l], d1=*(const float4*)&dT[l+4];
    float4 B0=*(const float4*)&Br[l], B1=*(const float4*)&Br[l+4];
    float4 C0=*(const float4*)&Cr[l], C1=*(const float4*)&Cr[l+4];
    ushort4 u0=*(const ushort4*)&ub[l], u1=*(const ushort4*)&ub[l+4];
    ushort4 x0=*(const ushort4*)&xb[l], x1=*(const ushort4*)&xb[l+4];
    while (l < segEnd) {
      int ln = l + 8;
      float4 nd0,nd1,nB0,nB1,nC0,nC1; ushort4 nu0,nu1,nx0,nx1;
      if (ln < segEnd) {
        nd0=*(const float4*)&dT[ln]; nd1=*(const float4*)&dT[ln+4];
        nB0=*(const float4*)&Br[ln]; nB1=*(const float4*)&Br[ln+4];
        nC0=*(const float4*)&Cr[ln]; nC1=*(const float4*)&Cr[ln+4];
        nu0=*(const ushort4*)&ub[ln]; nu1=*(const ushort4*)&ub[ln+4];
        nx0=*(const ushort4*)&xb[ln]; nx1=*(const ushort4*)&xb[ln+4];
      }
      float sufv = suf8sh[l >> 3];
      float dl[8] = {d0.x,d0.y,d0.z,d0.w,d1.x,d1.y,d1.z,d1.w};
      float Bv[8] = {B0.x,B0.y,B0.z,B0.w,B1.x,B1.y,B1.z,B1.w};
      float Cv[8] = {C0.x,C0.y,C0.z,C0.w,C1.x,C1.y,C1.z,C1.w};
      float uu[8] = {bf2f(u0.x),bf2f(u0.y),bf2f(u0.z),bf2f(u0.w),
                     bf2f(u1.x),bf2f(u1.y),bf2f(u1.z),bf2f(u1.w)};
      float xx[8] = {bf2f(x0.x),bf2f(x0.y),bf2f(x0.z),bf2f(x0.w),
                     bf2f(x1.x),bf2f(x1.y),bf2f(x1.z),bf2f(x1.w)};
      float cum = 0.f;
#pragma unroll
      for (int t=0;t<8;t++){
        cum += dl[t];
        float decay = __expf(-dl[t]*np1);
        s = fmaf(decay, s, dl[t]*uu[t]*Bv[t]);
        float gte = 1.f/(1.f + 1e-12f*__expf(np1*(sufv - cum)));  // overflow->inf->0
        float contrib = s*gte*Cv[t];
#pragma unroll
        for (int m=16;m>0;m>>=1) contrib += __shfl_xor(contrib, m);
        if (n == 0)
          zb[(size_t)(l+t)*PROJ] = f2bf((contrib + uu[t]*Ds)*xx[t]);
      }
      l = ln;
      d0=nd0; d1=nd1; B0=nB0; B1=nB1; C0=nC0; C1=nC1;
      u0=nu0; u1=nu1; x0=nx0; x1=nx1;
    }
  }
}

extern "C" void kernel_launch(void* const* d_in, const int* in_sizes, int n_in,
                              void* d_out, int out_size, void* d_ws, size_t ws_size,
                              hipStream_t stream)
{
  const float* x     = (const float*)d_in[0];
  const float* ln_g  = (const float*)d_in[1];
  const float* ln_b  = (const float*)d_in[2];
  const float* W1    = (const float*)d_in[3];
  const float* b1    = (const float*)d_in[4];
  const float* W2    = (const float*)d_in[5];
  const float* b2    = (const float*)d_in[6];
  const float* convk = (const float*)d_in[7];
  const float* convb = (const float*)d_in[8];
  const float* A_log = (const float*)d_in[9];
  const float* Dskip = (const float*)d_in[10];
  const float* WB    = (const float*)d_in[11];
  const float* bB    = (const float*)d_in[12];
  const float* WC    = (const float*)d_in[13];
  const float* bC    = (const float*)d_in[14];
  const float* Wd    = (const float*)d_in[15];
  const float* bd    = (const float*)d_in[16];
  const float* W3    = (const float*)d_in[17];
  const float* b3    = (const float*)d_in[18];

  char* w = (char*)d_ws;
  auto alloc = [&](size_t bytes){ char* p = w; w += (bytes + 255) & ~(size_t)255; return p; };
  unsigned short* Hbf    = (unsigned short*)alloc((size_t)ROWS*DMODEL*2);
  unsigned short* W12t   = (unsigned short*)alloc((size_t)2048*512*2);
  unsigned short* Wcatt  = (unsigned short*)alloc((size_t)NCATU*1024*2);
  unsigned short* W3t    = (unsigned short*)alloc((size_t)512*1024*2);
  float*          bias12 = (float*)alloc(2048*4);
  float*          biascat= (float*)alloc(NCATU*4);
  unsigned short* P12n   = (unsigned short*)alloc((size_t)ROWS*1024*2);
  unsigned short* ubf    = (unsigned short*)alloc((size_t)ROWS*PROJ*2);
  unsigned short* x2bf   = (unsigned short*)alloc((size_t)ROWS*PROJ*2);
  unsigned short* uT     = (unsigned short*)alloc((size_t)PROJ*ROWS*2);
  unsigned short* x2T    = (unsigned short*)alloc((size_t)PROJ*ROWS*2);
  float*          CT     = (float*)alloc((size_t)NCATU*ROWS*4);
  unsigned short* zbf    = (unsigned short*)alloc((size_t)ROWS*PROJ*2);
  float*          Pp     = (float*)alloc((size_t)2*ROWS*512*4);

  prep_ln_kernel<<<3661, 256, 0, stream>>>(W1,b1,W2,b2,Wd,bd,WB,bB,WC,bC,W3,
                                           W12t,Wcatt,W3t,bias12,biascat,
                                           x, ln_g, ln_b, Hbf);

  // gemm1: [4096][2048] = Hbf x W12t^T; split epilogue P12n / silu->x2bf  (2048 blocks, 64^2)
  dim3 g1(ROWS/64, 2048/64);
  gemm64<1><<<g1, 256, 0, stream>>>(Hbf, W12t, P12n, x2bf, bias12, ROWS, 2048, DMODEL, DMODEL);

  conv_silu_kernel<<<ROWS*256/256, 256, 0, stream>>>(P12n, convk, convb, ubf);

  // transpose u and x2 for the scan (coalesced both sides)
  dim3 gt(ROWS/32, PROJ/32, 2);
  utrans_kernel<<<gt, 256, 0, stream>>>(ubf, x2bf, uT, x2T);

  zmul_pre_kernel<<<(ROWS*PROJ/4)/256, 256, 0, stream>>>(ubf, x2bf, Dskip, zbf);

  // gemm2 (transposed out): CT[1088][4096] = Wcatt x ubf^T   (1088 blocks, 64^2)
  dim3 g2(NCATU/64, ROWS/64);
  gemm64<2><<<g2, 256, 0, stream>>>(Wcatt, ubf, CT, nullptr, biascat, NCATU, ROWS, PROJ, PROJ);

  // chunked suffix + scan (contiguous streams, double-buffered) -> overwrites zbf rows >= base
  sscan_kernel<<<2048, 256, 0, stream>>>(CT, uT, x2T, Dskip, A_log, zbf);

  // gemm3 split-K=2 (1024 blocks), then reduce(+bias+residual)
  dim3 g3(ROWS/64, 512/64, 2);
  gemm64<5><<<g3, 256, 0, stream>>>(zbf, W3t, Pp, nullptr, b3, ROWS, 512, 512, PROJ);
  reduce_kernel<<<(ROWS*512/4)/256, 256, 0, stream>>>(Pp, x, b3, (float*)d_out);
}

// Round 18
// 158.616 us; speedup vs baseline: 1.0069x; 1.0069x over previous
//
#include <hip/hip_runtime.h>
#include <stdint.h>

#define L_SEQ 2048
#define BATCH 2
#define DMODEL 512
#define PROJ 1024
#define NST 32
#define NCATU 1088  // 1024 (Wd) + 32 (WB) + 32 (WC)
#define ROWS (BATCH*L_SEQ)  // 4096
#define THRESH 50.0f        // suffix cutoff (nats)

typedef float f32x4 __attribute__((ext_vector_type(4)));
typedef short short8 __attribute__((ext_vector_type(8)));

__device__ inline float bf2f(unsigned short u){ uint32_t x=((uint32_t)u)<<16; float f; __builtin_memcpy(&f,&x,4); return f; }
__device__ inline unsigned short f2bf(float f){ uint32_t x; __builtin_memcpy(&x,&f,4); uint32_t r=x+0x7FFFu+((x>>16)&1u); return (unsigned short)(r>>16); }
__device__ inline float siluf(float x){ return x/(1.f+__expf(-x)); }
__device__ inline float softplusf(float x){ return x>20.f? x : log1pf(__expf(x)); }

#define AS1(p) ((const __attribute__((address_space(1))) void*)(p))
#define AS3(p) ((__attribute__((address_space(3))) void*)(p))

template<int N> __device__ inline void wait_vmcnt(){
  if constexpr (N==0)      asm volatile("s_waitcnt vmcnt(0)" ::: "memory");
  else if constexpr (N==4) asm volatile("s_waitcnt vmcnt(4)" ::: "memory");
  else if constexpr (N==8) asm volatile("s_waitcnt vmcnt(8)" ::: "memory");
  else                     asm volatile("s_waitcnt vmcnt(12)" ::: "memory");
}

// ---------------- merged weight-prep (LDS-tiled transposes) + LayerNorm ----------------
__global__ __launch_bounds__(256)
void prep_ln_kernel(const float* __restrict__ W1, const float* __restrict__ b1,
                    const float* __restrict__ W2, const float* __restrict__ b2,
                    const float* __restrict__ Wd, const float* __restrict__ bd,
                    const float* __restrict__ WB, const float* __restrict__ bB,
                    const float* __restrict__ WC, const float* __restrict__ bC,
                    const float* __restrict__ W3,
                    unsigned short* __restrict__ W12t, unsigned short* __restrict__ Wcatt,
                    unsigned short* __restrict__ W3t, float* __restrict__ bias12,
                    float* __restrict__ biascat,
                    const float* __restrict__ x, const float* __restrict__ ln_g,
                    const float* __restrict__ ln_b, unsigned short* __restrict__ H)
{
  __shared__ float tile[32][33];
  int bid = blockIdx.x;
  int lx = threadIdx.x & 31, ly = threadIdx.x >> 5;   // ly 0..7
  if (bid < 1024) {                    // W12t[2048][512] = (W1||W2)[512][2048]^T
    int kt = bid & 15, nt = bid >> 4;
    int k0 = kt*32, n0 = nt*32;
    const float* S = (n0 < 1024) ? W1 : W2;
    int nc = (n0 < 1024) ? n0 : n0 - 1024;
#pragma unroll
    for (int i=0;i<4;i++)
      tile[ly+i*8][lx] = S[(size_t)(k0+ly+i*8)*1024 + nc + lx];
    __syncthreads();
#pragma unroll
    for (int i=0;i<4;i++)
      W12t[(size_t)(n0+ly+i*8)*512 + k0 + lx] = f2bf(tile[lx][ly+i*8]);
    return;
  }
  if (bid < 2112) {                    // Wcatt[1088][1024] = (Wd|WB|WC)[1024][1088]^T
    int t = bid - 1024;
    int kt = t & 31, nt = t >> 5;      // 32 k-tiles, 34 n-tiles
    int k0 = kt*32, n0 = nt*32;
#pragma unroll
    for (int i=0;i<4;i++){
      int k = k0 + ly + i*8;
      float v;
      if (n0 < 1024)       v = Wd[(size_t)k*1024 + n0 + lx];
      else if (n0 == 1024) v = WB[(size_t)k*32 + lx];
      else                 v = WC[(size_t)k*32 + lx];
      tile[ly+i*8][lx] = v;
    }
    __syncthreads();
#pragma unroll
    for (int i=0;i<4;i++)
      Wcatt[(size_t)(n0+ly+i*8)*1024 + k0 + lx] = f2bf(tile[lx][ly+i*8]);
    return;
  }
  if (bid < 2624) {                    // W3t[512][1024] = W3[1024][512]^T
    int t = bid - 2112;
    int kt = t & 31, nt = t >> 5;      // 32 k-tiles, 16 n-tiles
    int k0 = kt*32, n0 = nt*32;
#pragma unroll
    for (int i=0;i<4;i++)
      tile[ly+i*8][lx] = W3[(size_t)(k0+ly+i*8)*512 + n0 + lx];
    __syncthreads();
#pragma unroll
    for (int i=0;i<4;i++)
      W3t[(size_t)(n0+ly+i*8)*1024 + k0 + lx] = f2bf(tile[lx][ly+i*8]);
    return;
  }
  if (bid < 2637) {
    int j = (bid - 2624)*256 + threadIdx.x;
    if (j < 2048) { bias12[j] = (j < 1024) ? b1[j] : b2[j-1024]; return; }
    j -= 2048;
    if (j < NCATU) biascat[j] = (j < 1024) ? bd[j] : (j < 1056) ? bB[j-1024] : bC[j-1056];
    return;
  }
  // LayerNorm
  int row = (bid - 2637)*4 + (threadIdx.x >> 6);
  int lane = threadIdx.x & 63;
  const float4* xr = (const float4*)(x + (size_t)row*DMODEL);
  float4 v0 = xr[lane];
  float4 v1 = xr[lane+64];
  float s = v0.x+v0.y+v0.z+v0.w + v1.x+v1.y+v1.z+v1.w;
  float q = v0.x*v0.x+v0.y*v0.y+v0.z*v0.z+v0.w*v0.w
          + v1.x*v1.x+v1.y*v1.y+v1.z*v1.z+v1.w*v1.w;
#pragma unroll
  for (int m=32;m>0;m>>=1){ s += __shfl_xor(s,m); q += __shfl_xor(q,m); }
  float mu = s*(1.f/DMODEL);
  float var = q*(1.f/DMODEL) - mu*mu;
  float rs = rsqrtf(var + 1e-3f);
  int c0 = lane*4, c1 = 256 + lane*4;
  float4 g0 = *(const float4*)&ln_g[c0]; float4 g1 = *(const float4*)&ln_g[c1];
  float4 t0 = *(const float4*)&ln_b[c0]; float4 t1 = *(const float4*)&ln_b[c1];
  ushort4 o0, o1;
  o0.x = f2bf((v0.x-mu)*rs*g0.x + t0.x);
  o0.y = f2bf((v0.y-mu)*rs*g0.y + t0.y);
  o0.z = f2bf((v0.z-mu)*rs*g0.z + t0.z);
  o0.w = f2bf((v0.w-mu)*rs*g0.w + t0.w);
  o1.x = f2bf((v1.x-mu)*rs*g1.x + t1.x);
  o1.y = f2bf((v1.y-mu)*rs*g1.y + t1.y);
  o1.z = f2bf((v1.z-mu)*rs*g1.z + t1.z);
  o1.w = f2bf((v1.w-mu)*rs*g1.w + t1.w);
  *(ushort4*)&H[(size_t)row*DMODEL + c0] = o0;
  *(ushort4*)&H[(size_t)row*DMODEL + c1] = o1;
}

// ---------------- 64x64 bf16 GEMM: triple-buffer, counted vmcnt (measured-best config) ----------------
// MODE 1: +bias[col]; col<1024 -> P12n bf16, col>=1024 -> x2bf = silu (Cv2).
// MODE 2 (transposed): +bias[row], softplus row<1024 -> fp32 CT[row*N+col].
// MODE 5: raw fp32 partial at Cv + z*M*N (split-K).
template<int MODE>
__global__ __launch_bounds__(256)
void gemm64(const unsigned short* __restrict__ A, const unsigned short* __restrict__ Bt,
            void* __restrict__ Cv, void* __restrict__ Cv2, const float* __restrict__ bias,
            int M, int N, int K, int Kfull)
{
  constexpr int BK = 64;
  constexpr int LPT = 4;
  __shared__ unsigned short As[3][64*BK];
  __shared__ unsigned short Bs[3][64*BK];
  int tid = threadIdx.x;
  int lane = tid & 63, wid = tid >> 6;
  int wm = wid >> 1, wn = wid & 1;
  int gx = gridDim.x;
  int nwg = gx * gridDim.y;
  int L = blockIdx.y*gx + blockIdx.x;
  int W = (L & 7)*(nwg >> 3) + (L >> 3);
  int bx = W % gx, by = W / gx;
  int m0 = bx*64, n0 = by*64;
  int kofs = blockIdx.z*K;

  f32x4 acc[2][2];
#pragma unroll
  for (int i=0;i<2;i++)
#pragma unroll
    for (int j=0;j<2;j++)
#pragma unroll
      for (int e=0;e<4;e++) acc[i][j][e] = 0.f;

  const unsigned short* ap[2];
  const unsigned short* bp[2];
#pragma unroll
  for (int j=0;j<2;j++){
    int s = tid + j*256;
    int row = s >> 3, kc = ((s & 7) ^ (row & 7)) * 8;
    ap[j] = A + (size_t)(m0+row)*Kfull + kofs + kc;
    bp[j] = Bt + (size_t)(n0+row)*Kfull + kofs + kc;
  }
  auto stage = [&](int buf){
#pragma unroll
    for (int j=0;j<2;j++){
      __builtin_amdgcn_global_load_lds(AS1(ap[j]), AS3(&As[buf][(size_t)(j*256 + wid*64)*8]), 16, 0, 0);
      ap[j] += BK;
    }
#pragma unroll
    for (int j=0;j<2;j++){
      __builtin_amdgcn_global_load_lds(AS1(bp[j]), AS3(&Bs[buf][(size_t)(j*256 + wid*64)*8]), 16, 0, 0);
      bp[j] += BK;
    }
  };
  stage(0); stage(1);
  int T = K/BK;
  int rb = 0, wb = 2;
  int r = lane & 15, kb = lane >> 4;
  for (int t = 0; t < T; ++t) {
    if (t+1 < T) wait_vmcnt<LPT>();
    else         wait_vmcnt<0>();
    __builtin_amdgcn_s_barrier();
    if (t+2 < T) { stage(wb); wb = (wb==2)?0:wb+1; }
#pragma unroll
    for (int ks=0; ks<2; ++ks) {
      int cx = (ks*4 + kb) ^ (r & 7);
      short8 af[2], bfr[2];
#pragma unroll
      for (int i=0;i<2;i++) af[i]  = *(const short8*)&As[rb][((wm*32 + i*16 + r)*8 + cx)*8];
#pragma unroll
      for (int j=0;j<2;j++) bfr[j] = *(const short8*)&Bs[rb][((wn*32 + j*16 + r)*8 + cx)*8];
      __builtin_amdgcn_s_setprio(1);
#pragma unroll
      for (int i=0;i<2;i++)
#pragma unroll
        for (int j=0;j<2;j++)
          acc[i][j] = __builtin_amdgcn_mfma_f32_16x16x32_bf16(af[i], bfr[j], acc[i][j], 0,0,0);
      __builtin_amdgcn_s_setprio(0);
    }
    rb = (rb==2)?0:rb+1;
  }
  int rr = (lane >> 4)*4, cc = lane & 15;
#pragma unroll
  for (int i=0;i<2;i++)
#pragma unroll
    for (int j=0;j<2;j++) {
      int col = n0 + wn*32 + j*16 + cc;
#pragma unroll
      for (int e=0;e<4;e++) {
        int row = m0 + wm*32 + i*16 + rr + e;
        float v = acc[i][j][e];
        if constexpr (MODE == 1) {
          v += bias[col];
          if (col < 1024) ((unsigned short*)Cv)[(size_t)row*1024 + col] = f2bf(v);
          else            ((unsigned short*)Cv2)[(size_t)row*1024 + col - 1024] = f2bf(siluf(v));
        } else if constexpr (MODE == 2) {
          v += bias[row];
          if (row < 1024) v = softplusf(v);
          ((float*)Cv)[(size_t)row*N + col] = v;
        } else {
          ((float*)Cv)[(size_t)blockIdx.z*M*N + (size_t)row*N + col] = v;
        }
      }
    }
}

// ---------------- split-K reduce + bias + residual ----------------
__global__ __launch_bounds__(256)
void reduce_kernel(const float* __restrict__ P, const float* __restrict__ x,
                   const float* __restrict__ b3, float* __restrict__ out)
{
  size_t i = ((size_t)blockIdx.x*256 + threadIdx.x)*4;
  int col = (int)(i & 511);
  float4 a = *(const float4*)&P[i];
  float4 b = *(const float4*)&P[(size_t)ROWS*512 + i];
  float4 xv = *(const float4*)&x[i];
  float4 bv = *(const float4*)&b3[col];
  float4 o;
  o.x = a.x + b.x + xv.x + bv.x;
  o.y = a.y + b.y + xv.y + bv.y;
  o.z = a.z + b.z + xv.z + bv.z;
  o.w = a.w + b.w + xv.w + bv.w;
  *(float4*)&out[i] = o;
}

// ---------------- causal depthwise conv (K=4) + SiLU (u path only) ----------------
__global__ __launch_bounds__(256)
void conv_silu_kernel(const unsigned short* __restrict__ P12n, const float* __restrict__ ck,
                      const float* __restrict__ cb, unsigned short* __restrict__ ubf)
{
  int gid = blockIdx.x*256 + threadIdx.x;   // ROWS * 256 tasks
  int c = (gid & 255)*4;
  int row = gid >> 8;
  int l = row & (L_SEQ-1);
  float4 bv = *(const float4*)&cb[c];
  float r0=bv.x, r1=bv.y, r2=bv.z, r3=bv.w;
#pragma unroll
  for (int t=0;t<4;t++){
    int lsrc = l - 3 + t;
    if (lsrc >= 0) {
      ushort4 xv = *(const ushort4*)&P12n[(size_t)(row-3+t)*1024 + c];
      float4 kv = *(const float4*)&ck[t*PROJ + c];
      r0 = fmaf(bf2f(xv.x),kv.x,r0);
      r1 = fmaf(bf2f(xv.y),kv.y,r1);
      r2 = fmaf(bf2f(xv.z),kv.z,r2);
      r3 = fmaf(bf2f(xv.w),kv.w,r3);
    }
  }
  ushort4 o;
  o.x=f2bf(siluf(r0)); o.y=f2bf(siluf(r1)); o.z=f2bf(siluf(r2)); o.w=f2bf(siluf(r3));
  *(ushort4*)&ubf[(size_t)row*PROJ + c] = o;
}

// ---------------- bf16 transpose: src[4096][1024] -> dst[1024][4096] (u and x2) ----------------
__global__ __launch_bounds__(256)
void utrans_kernel(const unsigned short* __restrict__ u, const unsigned short* __restrict__ x2,
                   unsigned short* __restrict__ uT, unsigned short* __restrict__ x2T)
{
  __shared__ unsigned short tile[32][33];
  const unsigned short* src = blockIdx.z ? x2 : u;
  unsigned short* dst = blockIdx.z ? x2T : uT;
  int r0 = blockIdx.x*32, c0 = blockIdx.y*32;
  int lx = threadIdx.x & 31, ly = threadIdx.x >> 5;
#pragma unroll
  for (int i=0;i<4;i++)
    tile[ly+i*8][lx] = src[(size_t)(r0+ly+i*8)*1024 + c0 + lx];
  __syncthreads();
#pragma unroll
  for (int i=0;i<4;i++)
    dst[(size_t)(c0+ly+i*8)*ROWS + r0 + lx] = tile[lx][ly+i*8];
}

// ---------------- zmul_pre: z = u*Dskip*x2 everywhere, COALESCED (sscan overwrites tail) ----------------
__global__ __launch_bounds__(256)
void zmul_pre_kernel(const unsigned short* __restrict__ ubf, const unsigned short* __restrict__ x2bf,
                     const float* __restrict__ Dskip, unsigned short* __restrict__ zbf)
{
  size_t i = ((size_t)blockIdx.x*256 + threadIdx.x)*4;
  int d = (int)(i & (PROJ-1));
  ushort4 uu = *(const ushort4*)&ubf[i];
  ushort4 xx = *(const ushort4*)&x2bf[i];
  float4 Dv = *(const float4*)&Dskip[d];
  ushort4 o;
  o.x = f2bf(bf2f(uu.x)*Dv.x*bf2f(xx.x));
  o.y = f2bf(bf2f(uu.y)*Dv.y*bf2f(xx.y));
  o.z = f2bf(bf2f(uu.z)*Dv.z*bf2f(xx.z));
  o.w = f2bf(bf2f(uu.w)*Dv.w*bf2f(xx.w));
  *(ushort4*)&zbf[i] = o;
}

// ---------------- wave-autonomous suffix-sum + windowed gated scan ----------------
// One WAVE per (b,d): phase A via width-64 shfl scan (NO barriers, NO LDS);
// suf8 boundary values live in 4 regs/lane, fetched by uniform-index cndmask+shfl.
// Lanes 32..63 mirror states 0..31 in the scan (redundant, harmless).
__global__ __launch_bounds__(256)
void sscan_kernel(const float* __restrict__ CT, const unsigned short* __restrict__ uT,
                  const unsigned short* __restrict__ x2T, const float* __restrict__ Dskip,
                  const float* __restrict__ A_log, unsigned short* __restrict__ zbf)
{
  int tid = threadIdx.x;
  int lane = tid & 63;
  int G = blockIdx.x*4 + (tid >> 6);
  int b = G >> 10, d = G & 1023;
  const float* dT = CT + (size_t)d*ROWS + b*L_SEQ;   // softplus'd delta row

  // ---- phase A: lane owns elements [lane*32, lane*32+32) ----
  float4 v4[8];
#pragma unroll
  for (int it=0; it<8; ++it) v4[it] = *(const float4*)&dT[lane*32 + it*4];
  // per-lane prefixes at 8-element boundaries (q=0..3) + local sum
  float p1 = v4[0].x+v4[0].y+v4[0].z+v4[0].w + v4[1].x+v4[1].y+v4[1].z+v4[1].w;
  float p2 = p1 + v4[2].x+v4[2].y+v4[2].z+v4[2].w + v4[3].x+v4[3].y+v4[3].z+v4[3].w;
  float p3 = p2 + v4[4].x+v4[4].y+v4[4].z+v4[4].w + v4[5].x+v4[5].y+v4[5].z+v4[5].w;
  float lsum = p3 + v4[6].x+v4[6].y+v4[6].z+v4[6].w + v4[7].x+v4[7].y+v4[7].z+v4[7].w;
  // width-64 inclusive scan of lsum
  float incl = lsum;
#pragma unroll
  for (int dlt=1; dlt<64; dlt<<=1){ float t = __shfl_up(incl, dlt, 64); if (lane >= dlt) incl += t; }
  float Tot = __shfl(incl, 63, 64);
  float excl = incl - lsum;
  // suf8 boundary values for this lane's 4 8-blocks
  float bnd0 = Tot - excl;
  float bnd1 = Tot - (excl + p1);
  float bnd2 = Tot - (excl + p2);
  float bnd3 = Tot - (excl + p3);
  // cnt = #positions with suffix >= THRESH
  int cnt = 0;
  {
    float run = excl;
    const float* vf = (const float*)v4;
#pragma unroll
    for (int i=0;i<32;i++){ cnt += (Tot - run >= THRESH) ? 1 : 0; run += vf[i]; }
  }
#pragma unroll
  for (int m=32;m>0;m>>=1) cnt += __shfl_xor(cnt, m, 64);
  int l0 = cnt > 0 ? cnt-1 : 0;
  int base = l0 & ~7;

  // ---- windowed gated scan ----
  int n = lane & 31;
  float np1 = __expf(A_log[d*NST + n]);      // -A[d,n] = n+1
  float Ds = Dskip[d];
  const float* Br = CT + (size_t)(1024+n)*ROWS + b*L_SEQ;
  const float* Cr = CT + (size_t)(1056+n)*ROWS + b*L_SEQ;
  const unsigned short* ub = uT  + (size_t)d*ROWS + b*L_SEQ;   // contiguous in l
  const unsigned short* xb = x2T + (size_t)d*ROWS + b*L_SEQ;
  unsigned short* zb = zbf + (size_t)b*L_SEQ*PROJ + d;
  float s = 0.f;
  for (int l = base; l < L_SEQ; l += 8) {
    int j = l >> 3, owner = j >> 2, q = j & 3;   // wave-uniform
    float bsel = (q==0) ? bnd0 : (q==1) ? bnd1 : (q==2) ? bnd2 : bnd3;
    float sufv = __shfl(bsel, owner, 64);
    float4 d0 = *(const float4*)&dT[l];
    float4 d1 = *(const float4*)&dT[l+4];
    float4 B0 = *(const float4*)&Br[l];
    float4 B1 = *(const float4*)&Br[l+4];
    float4 C0 = *(const float4*)&Cr[l];
    float4 C1 = *(const float4*)&Cr[l+4];
    ushort4 u0 = *(const ushort4*)&ub[l], u1 = *(const ushort4*)&ub[l+4];
    ushort4 x0 = *(const ushort4*)&xb[l], x1 = *(const ushort4*)&xb[l+4];
    float dl[8] = {d0.x,d0.y,d0.z,d0.w,d1.x,d1.y,d1.z,d1.w};
    float Bv[8] = {B0.x,B0.y,B0.z,B0.w,B1.x,B1.y,B1.z,B1.w};
    float Cv[8] = {C0.x,C0.y,C0.z,C0.w,C1.x,C1.y,C1.z,C1.w};
    float uu[8] = {bf2f(u0.x),bf2f(u0.y),bf2f(u0.z),bf2f(u0.w),
                   bf2f(u1.x),bf2f(u1.y),bf2f(u1.z),bf2f(u1.w)};
    float xx[8] = {bf2f(x0.x),bf2f(x0.y),bf2f(x0.z),bf2f(x0.w),
                   bf2f(x1.x),bf2f(x1.y),bf2f(x1.z),bf2f(x1.w)};
    float cum = 0.f;
#pragma unroll
    for (int t=0;t<8;t++){
      cum += dl[t];
      float decay = __expf(-dl[t]*np1);
      s = fmaf(decay, s, dl[t]*uu[t]*Bv[t]);
      float gte = 1.f/(1.f + 1e-12f*__expf(np1*(sufv - cum)));  // overflow->inf->0
      float contrib = s*gte*Cv[t];
#pragma unroll
      for (int m=16;m>0;m>>=1) contrib += __shfl_xor(contrib, m);
      if (lane == 0)
        zb[(size_t)(l+t)*PROJ] = f2bf((contrib + uu[t]*Ds)*xx[t]);
    }
  }
}

extern "C" void kernel_launch(void* const* d_in, const int* in_sizes, int n_in,
                              void* d_out, int out_size, void* d_ws, size_t ws_size,
                              hipStream_t stream)
{
  const float* x     = (const float*)d_in[0];
  const float* ln_g  = (const float*)d_in[1];
  const float* ln_b  = (const float*)d_in[2];
  const float* W1    = (const float*)d_in[3];
  const float* b1    = (const float*)d_in[4];
  const float* W2    = (const float*)d_in[5];
  const float* b2    = (const float*)d_in[6];
  const float* convk = (const float*)d_in[7];
  const float* convb = (const float*)d_in[8];
  const float* A_log = (const float*)d_in[9];
  const float* Dskip = (const float*)d_in[10];
  const float* WB    = (const float*)d_in[11];
  const float* bB    = (const float*)d_in[12];
  const float* WC    = (const float*)d_in[13];
  const float* bC    = (const float*)d_in[14];
  const float* Wd    = (const float*)d_in[15];
  const float* bd    = (const float*)d_in[16];
  const float* W3    = (const float*)d_in[17];
  const float* b3    = (const float*)d_in[18];

  char* w = (char*)d_ws;
  auto alloc = [&](size_t bytes){ char* p = w; w += (bytes + 255) & ~(size_t)255; return p; };
  unsigned short* Hbf    = (unsigned short*)alloc((size_t)ROWS*DMODEL*2);
  unsigned short* W12t   = (unsigned short*)alloc((size_t)2048*512*2);
  unsigned short* Wcatt  = (unsigned short*)alloc((size_t)NCATU*1024*2);
  unsigned short* W3t    = (unsigned short*)alloc((size_t)512*1024*2);
  float*          bias12 = (float*)alloc(2048*4);
  float*          biascat= (float*)alloc(NCATU*4);
  unsigned short* P12n   = (unsigned short*)alloc((size_t)ROWS*1024*2);
  unsigned short* ubf    = (unsigned short*)alloc((size_t)ROWS*PROJ*2);
  unsigned short* x2bf   = (unsigned short*)alloc((size_t)ROWS*PROJ*2);
  unsigned short* uT     = (unsigned short*)alloc((size_t)PROJ*ROWS*2);
  unsigned short* x2T    = (unsigned short*)alloc((size_t)PROJ*ROWS*2);
  float*          CT     = (float*)alloc((size_t)NCATU*ROWS*4);
  unsigned short* zbf    = (unsigned short*)alloc((size_t)ROWS*PROJ*2);
  float*          Pp     = (float*)alloc((size_t)2*ROWS*512*4);

  prep_ln_kernel<<<3661, 256, 0, stream>>>(W1,b1,W2,b2,Wd,bd,WB,bB,WC,bC,W3,
                                           W12t,Wcatt,W3t,bias12,biascat,
                                           x, ln_g, ln_b, Hbf);

  // gemm1: [4096][2048] = Hbf x W12t^T; split epilogue P12n / silu->x2bf  (2048 blocks, 64^2)
  dim3 g1(ROWS/64, 2048/64);
  gemm64<1><<<g1, 256, 0, stream>>>(Hbf, W12t, P12n, x2bf, bias12, ROWS, 2048, DMODEL, DMODEL);

  conv_silu_kernel<<<ROWS*256/256, 256, 0, stream>>>(P12n, convk, convb, ubf);

  // transpose u and x2 for the scan (coalesced both sides)
  dim3 gt(ROWS/32, PROJ/32, 2);
  utrans_kernel<<<gt, 256, 0, stream>>>(ubf, x2bf, uT, x2T);

  zmul_pre_kernel<<<(ROWS*PROJ/4)/256, 256, 0, stream>>>(ubf, x2bf, Dskip, zbf);

  // gemm2 (transposed out): CT[1088][4096] = Wcatt x ubf^T   (1088 blocks, 64^2)
  dim3 g2(NCATU/64, ROWS/64);
  gemm64<2><<<g2, 256, 0, stream>>>(Wcatt, ubf, CT, nullptr, biascat, NCATU, ROWS, PROJ, PROJ);

  // wave-autonomous suffix + windowed scan -> overwrites zbf rows >= base
  sscan_kernel<<<512, 256, 0, stream>>>(CT, uT, x2T, Dskip, A_log, zbf);

  // gemm3 split-K=2 (1024 blocks), then reduce(+bias+residual)
  dim3 g3(ROWS/64, 512/64, 2);
  gemm64<5><<<g3, 256, 0, stream>>>(zbf, W3t, Pp, nullptr, b3, ROWS, 512, 512, PROJ);
  reduce_kernel<<<(ROWS*512/4)/256, 256, 0, stream>>>(Pp, x, b3, (float*)d_out);
}

// Round 19
// 144.092 us; speedup vs baseline: 1.1084x; 1.1008x over previous
//
#include <hip/hip_runtime.h>
#include <stdint.h>

#define L_SEQ 2048
#define BATCH 2
#define DMODEL 512
#define PROJ 1024
#define NST 32
#define NCATU 1088  // 1024 (Wd) + 32 (WB) + 32 (WC)
#define ROWS (BATCH*L_SEQ)  // 4096
#define THRESH 50.0f        // suffix cutoff (nats)

typedef float f32x4 __attribute__((ext_vector_type(4)));
typedef short short8 __attribute__((ext_vector_type(8)));

__device__ inline float bf2f(unsigned short u){ uint32_t x=((uint32_t)u)<<16; float f; __builtin_memcpy(&f,&x,4); return f; }
__device__ inline unsigned short f2bf(float f){ uint32_t x; __builtin_memcpy(&x,&f,4); uint32_t r=x+0x7FFFu+((x>>16)&1u); return (unsigned short)(r>>16); }
__device__ inline float siluf(float x){ return x/(1.f+__expf(-x)); }
__device__ inline float softplusf(float x){ return x>20.f? x : log1pf(__expf(x)); }

#define AS1(p) ((const __attribute__((address_space(1))) void*)(p))
#define AS3(p) ((__attribute__((address_space(3))) void*)(p))

template<int N> __device__ inline void wait_vmcnt(){
  if constexpr (N==0)      asm volatile("s_waitcnt vmcnt(0)" ::: "memory");
  else if constexpr (N==4) asm volatile("s_waitcnt vmcnt(4)" ::: "memory");
  else if constexpr (N==8) asm volatile("s_waitcnt vmcnt(8)" ::: "memory");
  else                     asm volatile("s_waitcnt vmcnt(12)" ::: "memory");
}

// ---------------- merged weight-prep (LDS-tiled transposes) + LayerNorm ----------------
__global__ __launch_bounds__(256)
void prep_ln_kernel(const float* __restrict__ W1, const float* __restrict__ b1,
                    const float* __restrict__ W2, const float* __restrict__ b2,
                    const float* __restrict__ Wd, const float* __restrict__ bd,
                    const float* __restrict__ WB, const float* __restrict__ bB,
                    const float* __restrict__ WC, const float* __restrict__ bC,
                    const float* __restrict__ W3,
                    unsigned short* __restrict__ W12t, unsigned short* __restrict__ Wcatt,
                    unsigned short* __restrict__ W3t, float* __restrict__ bias12,
                    float* __restrict__ biascat,
                    const float* __restrict__ x, const float* __restrict__ ln_g,
                    const float* __restrict__ ln_b, unsigned short* __restrict__ H)
{
  __shared__ float tile[32][33];
  int bid = blockIdx.x;
  int lx = threadIdx.x & 31, ly = threadIdx.x >> 5;   // ly 0..7
  if (bid < 1024) {                    // W12t[2048][512] = (W1||W2)[512][2048]^T
    int kt = bid & 15, nt = bid >> 4;
    int k0 = kt*32, n0 = nt*32;
    const float* S = (n0 < 1024) ? W1 : W2;
    int nc = (n0 < 1024) ? n0 : n0 - 1024;
#pragma unroll
    for (int i=0;i<4;i++)
      tile[ly+i*8][lx] = S[(size_t)(k0+ly+i*8)*1024 + nc + lx];
    __syncthreads();
#pragma unroll
    for (int i=0;i<4;i++)
      W12t[(size_t)(n0+ly+i*8)*512 + k0 + lx] = f2bf(tile[lx][ly+i*8]);
    return;
  }
  if (bid < 2112) {                    // Wcatt[1088][1024] = (Wd|WB|WC)[1024][1088]^T
    int t = bid - 1024;
    int kt = t & 31, nt = t >> 5;      // 32 k-tiles, 34 n-tiles
    int k0 = kt*32, n0 = nt*32;
#pragma unroll
    for (int i=0;i<4;i++){
      int k = k0 + ly + i*8;
      float v;
      if (n0 < 1024)       v = Wd[(size_t)k*1024 + n0 + lx];
      else if (n0 == 1024) v = WB[(size_t)k*32 + lx];
      else                 v = WC[(size_t)k*32 + lx];
      tile[ly+i*8][lx] = v;
    }
    __syncthreads();
#pragma unroll
    for (int i=0;i<4;i++)
      Wcatt[(size_t)(n0+ly+i*8)*1024 + k0 + lx] = f2bf(tile[lx][ly+i*8]);
    return;
  }
  if (bid < 2624) {                    // W3t[512][1024] = W3[1024][512]^T
    int t = bid - 2112;
    int kt = t & 31, nt = t >> 5;      // 32 k-tiles, 16 n-tiles
    int k0 = kt*32, n0 = nt*32;
#pragma unroll
    for (int i=0;i<4;i++)
      tile[ly+i*8][lx] = W3[(size_t)(k0+ly+i*8)*512 + n0 + lx];
    __syncthreads();
#pragma unroll
    for (int i=0;i<4;i++)
      W3t[(size_t)(n0+ly+i*8)*1024 + k0 + lx] = f2bf(tile[lx][ly+i*8]);
    return;
  }
  if (bid < 2637) {
    int j = (bid - 2624)*256 + threadIdx.x;
    if (j < 2048) { bias12[j] = (j < 1024) ? b1[j] : b2[j-1024]; return; }
    j -= 2048;
    if (j < NCATU) biascat[j] = (j < 1024) ? bd[j] : (j < 1056) ? bB[j-1024] : bC[j-1056];
    return;
  }
  // LayerNorm
  int row = (bid - 2637)*4 + (threadIdx.x >> 6);
  int lane = threadIdx.x & 63;
  const float4* xr = (const float4*)(x + (size_t)row*DMODEL);
  float4 v0 = xr[lane];
  float4 v1 = xr[lane+64];
  float s = v0.x+v0.y+v0.z+v0.w + v1.x+v1.y+v1.z+v1.w;
  float q = v0.x*v0.x+v0.y*v0.y+v0.z*v0.z+v0.w*v0.w
          + v1.x*v1.x+v1.y*v1.y+v1.z*v1.z+v1.w*v1.w;
#pragma unroll
  for (int m=32;m>0;m>>=1){ s += __shfl_xor(s,m); q += __shfl_xor(q,m); }
  float mu = s*(1.f/DMODEL);
  float var = q*(1.f/DMODEL) - mu*mu;
  float rs = rsqrtf(var + 1e-3f);
  int c0 = lane*4, c1 = 256 + lane*4;
  float4 g0 = *(const float4*)&ln_g[c0]; float4 g1 = *(const float4*)&ln_g[c1];
  float4 t0 = *(const float4*)&ln_b[c0]; float4 t1 = *(const float4*)&ln_b[c1];
  ushort4 o0, o1;
  o0.x = f2bf((v0.x-mu)*rs*g0.x + t0.x);
  o0.y = f2bf((v0.y-mu)*rs*g0.y + t0.y);
  o0.z = f2bf((v0.z-mu)*rs*g0.z + t0.z);
  o0.w = f2bf((v0.w-mu)*rs*g0.w + t0.w);
  o1.x = f2bf((v1.x-mu)*rs*g1.x + t1.x);
  o1.y = f2bf((v1.y-mu)*rs*g1.y + t1.y);
  o1.z = f2bf((v1.z-mu)*rs*g1.z + t1.z);
  o1.w = f2bf((v1.w-mu)*rs*g1.w + t1.w);
  *(ushort4*)&H[(size_t)row*DMODEL + c0] = o0;
  *(ushort4*)&H[(size_t)row*DMODEL + c1] = o1;
}

// ---------------- 64x64 bf16 GEMM: triple-buffer, counted vmcnt (measured-best config) ----------------
// MODE 1: +bias[col]; col<1024 -> P12n bf16, col>=1024 -> x2bf = silu (Cv2).
// MODE 2 (transposed): +bias[row], softplus row<1024 -> fp32 CT[row*N+col].
// MODE 5: raw fp32 partial at Cv + z*M*N (split-K).
template<int MODE>
__global__ __launch_bounds__(256)
void gemm64(const unsigned short* __restrict__ A, const unsigned short* __restrict__ Bt,
            void* __restrict__ Cv, void* __restrict__ Cv2, const float* __restrict__ bias,
            int M, int N, int K, int Kfull)
{
  constexpr int BK = 64;
  constexpr int LPT = 4;
  __shared__ unsigned short As[3][64*BK];
  __shared__ unsigned short Bs[3][64*BK];
  int tid = threadIdx.x;
  int lane = tid & 63, wid = tid >> 6;
  int wm = wid >> 1, wn = wid & 1;
  int gx = gridDim.x;
  int nwg = gx * gridDim.y;
  int L = blockIdx.y*gx + blockIdx.x;
  int W = (L & 7)*(nwg >> 3) + (L >> 3);
  int bx = W % gx, by = W / gx;
  int m0 = bx*64, n0 = by*64;
  int kofs = blockIdx.z*K;

  f32x4 acc[2][2];
#pragma unroll
  for (int i=0;i<2;i++)
#pragma unroll
    for (int j=0;j<2;j++)
#pragma unroll
      for (int e=0;e<4;e++) acc[i][j][e] = 0.f;

  const unsigned short* ap[2];
  const unsigned short* bp[2];
#pragma unroll
  for (int j=0;j<2;j++){
    int s = tid + j*256;
    int row = s >> 3, kc = ((s & 7) ^ (row & 7)) * 8;
    ap[j] = A + (size_t)(m0+row)*Kfull + kofs + kc;
    bp[j] = Bt + (size_t)(n0+row)*Kfull + kofs + kc;
  }
  auto stage = [&](int buf){
#pragma unroll
    for (int j=0;j<2;j++){
      __builtin_amdgcn_global_load_lds(AS1(ap[j]), AS3(&As[buf][(size_t)(j*256 + wid*64)*8]), 16, 0, 0);
      ap[j] += BK;
    }
#pragma unroll
    for (int j=0;j<2;j++){
      __builtin_amdgcn_global_load_lds(AS1(bp[j]), AS3(&Bs[buf][(size_t)(j*256 + wid*64)*8]), 16, 0, 0);
      bp[j] += BK;
    }
  };
  stage(0); stage(1);
  int T = K/BK;
  int rb = 0, wb = 2;
  int r = lane & 15, kb = lane >> 4;
  for (int t = 0; t < T; ++t) {
    if (t+1 < T) wait_vmcnt<LPT>();
    else         wait_vmcnt<0>();
    __builtin_amdgcn_s_barrier();
    if (t+2 < T) { stage(wb); wb = (wb==2)?0:wb+1; }
#pragma unroll
    for (int ks=0; ks<2; ++ks) {
      int cx = (ks*4 + kb) ^ (r & 7);
      short8 af[2], bfr[2];
#pragma unroll
      for (int i=0;i<2;i++) af[i]  = *(const short8*)&As[rb][((wm*32 + i*16 + r)*8 + cx)*8];
#pragma unroll
      for (int j=0;j<2;j++) bfr[j] = *(const short8*)&Bs[rb][((wn*32 + j*16 + r)*8 + cx)*8];
      __builtin_amdgcn_s_setprio(1);
#pragma unroll
      for (int i=0;i<2;i++)
#pragma unroll
        for (int j=0;j<2;j++)
          acc[i][j] = __builtin_amdgcn_mfma_f32_16x16x32_bf16(af[i], bfr[j], acc[i][j], 0,0,0);
      __builtin_amdgcn_s_setprio(0);
    }
    rb = (rb==2)?0:rb+1;
  }
  int rr = (lane >> 4)*4, cc = lane & 15;
#pragma unroll
  for (int i=0;i<2;i++)
#pragma unroll
    for (int j=0;j<2;j++) {
      int col = n0 + wn*32 + j*16 + cc;
#pragma unroll
      for (int e=0;e<4;e++) {
        int row = m0 + wm*32 + i*16 + rr + e;
        float v = acc[i][j][e];
        if constexpr (MODE == 1) {
          v += bias[col];
          if (col < 1024) ((unsigned short*)Cv)[(size_t)row*1024 + col] = f2bf(v);
          else            ((unsigned short*)Cv2)[(size_t)row*1024 + col - 1024] = f2bf(siluf(v));
        } else if constexpr (MODE == 2) {
          v += bias[row];
          if (row < 1024) v = softplusf(v);
          ((float*)Cv)[(size_t)row*N + col] = v;
        } else {
          ((float*)Cv)[(size_t)blockIdx.z*M*N + (size_t)row*N + col] = v;
        }
      }
    }
}

// ---------------- split-K reduce + bias + residual ----------------
__global__ __launch_bounds__(256)
void reduce_kernel(const float* __restrict__ P, const float* __restrict__ x,
                   const float* __restrict__ b3, float* __restrict__ out)
{
  size_t i = ((size_t)blockIdx.x*256 + threadIdx.x)*4;
  int col = (int)(i & 511);
  float4 a = *(const float4*)&P[i];
  float4 b = *(const float4*)&P[(size_t)ROWS*512 + i];
  float4 xv = *(const float4*)&x[i];
  float4 bv = *(const float4*)&b3[col];
  float4 o;
  o.x = a.x + b.x + xv.x + bv.x;
  o.y = a.y + b.y + xv.y + bv.y;
  o.z = a.z + b.z + xv.z + bv.z;
  o.w = a.w + b.w + xv.w + bv.w;
  *(float4*)&out[i] = o;
}

// ---------------- causal depthwise conv (K=4) + SiLU (u path only) ----------------
__global__ __launch_bounds__(256)
void conv_silu_kernel(const unsigned short* __restrict__ P12n, const float* __restrict__ ck,
                      const float* __restrict__ cb, unsigned short* __restrict__ ubf)
{
  int gid = blockIdx.x*256 + threadIdx.x;   // ROWS * 256 tasks
  int c = (gid & 255)*4;
  int row = gid >> 8;
  int l = row & (L_SEQ-1);
  float4 bv = *(const float4*)&cb[c];
  float r0=bv.x, r1=bv.y, r2=bv.z, r3=bv.w;
#pragma unroll
  for (int t=0;t<4;t++){
    int lsrc = l - 3 + t;
    if (lsrc >= 0) {
      ushort4 xv = *(const ushort4*)&P12n[(size_t)(row-3+t)*1024 + c];
      float4 kv = *(const float4*)&ck[t*PROJ + c];
      r0 = fmaf(bf2f(xv.x),kv.x,r0);
      r1 = fmaf(bf2f(xv.y),kv.y,r1);
      r2 = fmaf(bf2f(xv.z),kv.z,r2);
      r3 = fmaf(bf2f(xv.w),kv.w,r3);
    }
  }
  ushort4 o;
  o.x=f2bf(siluf(r0)); o.y=f2bf(siluf(r1)); o.z=f2bf(siluf(r2)); o.w=f2bf(siluf(r3));
  *(ushort4*)&ubf[(size_t)row*PROJ + c] = o;
}

// ---------------- bf16 transpose: src[4096][1024] -> dst[1024][4096] (u and x2) ----------------
__global__ __launch_bounds__(256)
void utrans_kernel(const unsigned short* __restrict__ u, const unsigned short* __restrict__ x2,
                   unsigned short* __restrict__ uT, unsigned short* __restrict__ x2T)
{
  __shared__ unsigned short tile[32][33];
  const unsigned short* src = blockIdx.z ? x2 : u;
  unsigned short* dst = blockIdx.z ? x2T : uT;
  int r0 = blockIdx.x*32, c0 = blockIdx.y*32;
  int lx = threadIdx.x & 31, ly = threadIdx.x >> 5;
#pragma unroll
  for (int i=0;i<4;i++)
    tile[ly+i*8][lx] = src[(size_t)(r0+ly+i*8)*1024 + c0 + lx];
  __syncthreads();
#pragma unroll
  for (int i=0;i<4;i++)
    dst[(size_t)(c0+ly+i*8)*ROWS + r0 + lx] = tile[lx][ly+i*8];
}

// ---------------- zmul_pre: z = u*Dskip*x2 everywhere, COALESCED (sscan overwrites tail) ----------------
__global__ __launch_bounds__(256)
void zmul_pre_kernel(const unsigned short* __restrict__ ubf, const unsigned short* __restrict__ x2bf,
                     const float* __restrict__ Dskip, unsigned short* __restrict__ zbf)
{
  size_t i = ((size_t)blockIdx.x*256 + threadIdx.x)*4;
  int d = (int)(i & (PROJ-1));
  ushort4 uu = *(const ushort4*)&ubf[i];
  ushort4 xx = *(const ushort4*)&x2bf[i];
  float4 Dv = *(const float4*)&Dskip[d];
  ushort4 o;
  o.x = f2bf(bf2f(uu.x)*Dv.x*bf2f(xx.x));
  o.y = f2bf(bf2f(uu.y)*Dv.y*bf2f(xx.y));
  o.z = f2bf(bf2f(uu.z)*Dv.z*bf2f(xx.z));
  o.w = f2bf(bf2f(uu.w)*Dv.w*bf2f(xx.w));
  *(ushort4*)&zbf[i] = o;
}

// ---------------- wave-autonomous suffix-sum + windowed gated scan ----------------
// One WAVE per (b,d). KEY (r18 lesson): the per-step 5-deep shfl_xor reduce was
// ~600 cyc of serial DS latency per step -- the 42us floor. Now each 8-step block
// accumulates c8[0..7] in registers (serial chain = cheap fma/exp only) and does
// ONE batched butterfly reduce (8 independent chains pipeline each level).
__global__ __launch_bounds__(256)
void sscan_kernel(const float* __restrict__ CT, const unsigned short* __restrict__ uT,
                  const unsigned short* __restrict__ x2T, const float* __restrict__ Dskip,
                  const float* __restrict__ A_log, unsigned short* __restrict__ zbf)
{
  int tid = threadIdx.x;
  int lane = tid & 63;
  int G = blockIdx.x*4 + (tid >> 6);
  int b = G >> 10, d = G & 1023;
  const float* dT = CT + (size_t)d*ROWS + b*L_SEQ;   // softplus'd delta row

  // ---- phase A: lane owns elements [lane*32, lane*32+32) ----
  float4 v4[8];
#pragma unroll
  for (int it=0; it<8; ++it) v4[it] = *(const float4*)&dT[lane*32 + it*4];
  float p1 = v4[0].x+v4[0].y+v4[0].z+v4[0].w + v4[1].x+v4[1].y+v4[1].z+v4[1].w;
  float p2 = p1 + v4[2].x+v4[2].y+v4[2].z+v4[2].w + v4[3].x+v4[3].y+v4[3].z+v4[3].w;
  float p3 = p2 + v4[4].x+v4[4].y+v4[4].z+v4[4].w + v4[5].x+v4[5].y+v4[5].z+v4[5].w;
  float lsum = p3 + v4[6].x+v4[6].y+v4[6].z+v4[6].w + v4[7].x+v4[7].y+v4[7].z+v4[7].w;
  float incl = lsum;
#pragma unroll
  for (int dlt=1; dlt<64; dlt<<=1){ float t = __shfl_up(incl, dlt, 64); if (lane >= dlt) incl += t; }
  float Tot = __shfl(incl, 63, 64);
  float excl = incl - lsum;
  float bnd0 = Tot - excl;
  float bnd1 = Tot - (excl + p1);
  float bnd2 = Tot - (excl + p2);
  float bnd3 = Tot - (excl + p3);
  int cnt = 0;
  {
    float run = excl;
    const float* vf = (const float*)v4;
#pragma unroll
    for (int i=0;i<32;i++){ cnt += (Tot - run >= THRESH) ? 1 : 0; run += vf[i]; }
  }
#pragma unroll
  for (int m=32;m>0;m>>=1) cnt += __shfl_xor(cnt, m, 64);
  int l0 = cnt > 0 ? cnt-1 : 0;
  int base = l0 & ~7;

  // ---- windowed gated scan (batched reduce) ----
  int n = lane & 31;
  float np1 = __expf(A_log[d*NST + n]);      // -A[d,n] = n+1
  float Ds = Dskip[d];
  const float* Br = CT + (size_t)(1024+n)*ROWS + b*L_SEQ;
  const float* Cr = CT + (size_t)(1056+n)*ROWS + b*L_SEQ;
  const unsigned short* ub = uT  + (size_t)d*ROWS + b*L_SEQ;   // contiguous in l
  const unsigned short* xb = x2T + (size_t)d*ROWS + b*L_SEQ;
  unsigned short* zb = zbf + (size_t)b*L_SEQ*PROJ + d;
  float s = 0.f;
  for (int l = base; l < L_SEQ; l += 8) {
    int j = l >> 3, owner = j >> 2, q = j & 3;   // wave-uniform
    float bsel = (q==0) ? bnd0 : (q==1) ? bnd1 : (q==2) ? bnd2 : bnd3;
    float sufv = __shfl(bsel, owner, 64);
    float4 d0 = *(const float4*)&dT[l];
    float4 d1 = *(const float4*)&dT[l+4];
    float4 B0 = *(const float4*)&Br[l];
    float4 B1 = *(const float4*)&Br[l+4];
    float4 C0 = *(const float4*)&Cr[l];
    float4 C1 = *(const float4*)&Cr[l+4];
    ushort4 u0 = *(const ushort4*)&ub[l], u1 = *(const ushort4*)&ub[l+4];
    ushort4 x0 = *(const ushort4*)&xb[l], x1 = *(const ushort4*)&xb[l+4];
    float dl[8] = {d0.x,d0.y,d0.z,d0.w,d1.x,d1.y,d1.z,d1.w};
    float Bv[8] = {B0.x,B0.y,B0.z,B0.w,B1.x,B1.y,B1.z,B1.w};
    float Cv[8] = {C0.x,C0.y,C0.z,C0.w,C1.x,C1.y,C1.z,C1.w};
    float uu[8] = {bf2f(u0.x),bf2f(u0.y),bf2f(u0.z),bf2f(u0.w),
                   bf2f(u1.x),bf2f(u1.y),bf2f(u1.z),bf2f(u1.w)};
    float xx[8] = {bf2f(x0.x),bf2f(x0.y),bf2f(x0.z),bf2f(x0.w),
                   bf2f(x1.x),bf2f(x1.y),bf2f(x1.z),bf2f(x1.w)};
    float c8[8];
    float cum = 0.f;
#pragma unroll
    for (int t=0;t<8;t++){
      cum += dl[t];
      float decay = __expf(-dl[t]*np1);
      s = fmaf(decay, s, dl[t]*uu[t]*Bv[t]);
      float gte = 1.f/(1.f + 1e-12f*__expf(np1*(sufv - cum)));  // overflow->inf->0
      c8[t] = s*gte*Cv[t];
    }
    // batched butterfly: 8 independent chains per level -> latency ~5 shfl total
#pragma unroll
    for (int m=16;m>0;m>>=1){
#pragma unroll
      for (int t=0;t<8;t++) c8[t] += __shfl_xor(c8[t], m);
    }
    if (lane == 0) {
#pragma unroll
      for (int t=0;t<8;t++)
        zb[(size_t)(l+t)*PROJ] = f2bf((c8[t] + uu[t]*Ds)*xx[t]);
    }
  }
}

extern "C" void kernel_launch(void* const* d_in, const int* in_sizes, int n_in,
                              void* d_out, int out_size, void* d_ws, size_t ws_size,
                              hipStream_t stream)
{
  const float* x     = (const float*)d_in[0];
  const float* ln_g  = (const float*)d_in[1];
  const float* ln_b  = (const float*)d_in[2];
  const float* W1    = (const float*)d_in[3];
  const float* b1    = (const float*)d_in[4];
  const float* W2    = (const float*)d_in[5];
  const float* b2    = (const float*)d_in[6];
  const float* convk = (const float*)d_in[7];
  const float* convb = (const float*)d_in[8];
  const float* A_log = (const float*)d_in[9];
  const float* Dskip = (const float*)d_in[10];
  const float* WB    = (const float*)d_in[11];
  const float* bB    = (const float*)d_in[12];
  const float* WC    = (const float*)d_in[13];
  const float* bC    = (const float*)d_in[14];
  const float* Wd    = (const float*)d_in[15];
  const float* bd    = (const float*)d_in[16];
  const float* W3    = (const float*)d_in[17];
  const float* b3    = (const float*)d_in[18];

  char* w = (char*)d_ws;
  auto alloc = [&](size_t bytes){ char* p = w; w += (bytes + 255) & ~(size_t)255; return p; };
  unsigned short* Hbf    = (unsigned short*)alloc((size_t)ROWS*DMODEL*2);
  unsigned short* W12t   = (unsigned short*)alloc((size_t)2048*512*2);
  unsigned short* Wcatt  = (unsigned short*)alloc((size_t)NCATU*1024*2);
  unsigned short* W3t    = (unsigned short*)alloc((size_t)512*1024*2);
  float*          bias12 = (float*)alloc(2048*4);
  float*          biascat= (float*)alloc(NCATU*4);
  unsigned short* P12n   = (unsigned short*)alloc((size_t)ROWS*1024*2);
  unsigned short* ubf    = (unsigned short*)alloc((size_t)ROWS*PROJ*2);
  unsigned short* x2bf   = (unsigned short*)alloc((size_t)ROWS*PROJ*2);
  unsigned short* uT     = (unsigned short*)alloc((size_t)PROJ*ROWS*2);
  unsigned short* x2T    = (unsigned short*)alloc((size_t)PROJ*ROWS*2);
  float*          CT     = (float*)alloc((size_t)NCATU*ROWS*4);
  unsigned short* zbf    = (unsigned short*)alloc((size_t)ROWS*PROJ*2);
  float*          Pp     = (float*)alloc((size_t)2*ROWS*512*4);

  prep_ln_kernel<<<3661, 256, 0, stream>>>(W1,b1,W2,b2,Wd,bd,WB,bB,WC,bC,W3,
                                           W12t,Wcatt,W3t,bias12,biascat,
                                           x, ln_g, ln_b, Hbf);

  // gemm1: [4096][2048] = Hbf x W12t^T; split epilogue P12n / silu->x2bf  (2048 blocks, 64^2)
  dim3 g1(ROWS/64, 2048/64);
  gemm64<1><<<g1, 256, 0, stream>>>(Hbf, W12t, P12n, x2bf, bias12, ROWS, 2048, DMODEL, DMODEL);

  conv_silu_kernel<<<ROWS*256/256, 256, 0, stream>>>(P12n, convk, convb, ubf);

  // transpose u and x2 for the scan (coalesced both sides)
  dim3 gt(ROWS/32, PROJ/32, 2);
  utrans_kernel<<<gt, 256, 0, stream>>>(ubf, x2bf, uT, x2T);

  zmul_pre_kernel<<<(ROWS*PROJ/4)/256, 256, 0, stream>>>(ubf, x2bf, Dskip, zbf);

  // gemm2 (transposed out): CT[1088][4096] = Wcatt x ubf^T   (1088 blocks, 64^2)
  dim3 g2(NCATU/64, ROWS/64);
  gemm64<2><<<g2, 256, 0, stream>>>(Wcatt, ubf, CT, nullptr, biascat, NCATU, ROWS, PROJ, PROJ);

  // wave-autonomous suffix + windowed scan (batched reduce) -> overwrites zbf rows >= base
  sscan_kernel<<<512, 256, 0, stream>>>(CT, uT, x2T, Dskip, A_log, zbf);

  // gemm3 split-K=2 (1024 blocks), then reduce(+bias+residual)
  dim3 g3(ROWS/64, 512/64, 2);
  gemm64<5><<<g3, 256, 0, stream>>>(zbf, W3t, Pp, nullptr, b3, ROWS, 512, 512, PROJ);
  reduce_kernel<<<(ROWS*512/4)/256, 256, 0, stream>>>(Pp, x, b3, (float*)d_out);
}